// Round 1
// baseline (569.400 us; speedup 1.0000x reference)
//
#include <hip/hip_runtime.h>
#include <cmath>

#define IN_CH 128
#define OUT_CH 128
#define KDIM 512   // Z row: x(128) | sum(128) | mean(128) | max(128)
#define NDIM 384   // G row: id(128) | amp(128) | att(128)

// ---------------- CSR build ----------------

__global__ void degree_kernel(const int* __restrict__ ei, int* __restrict__ degree, int E) {
    int e = blockIdx.x * blockDim.x + threadIdx.x;
    if (e < E) atomicAdd(&degree[ei[E + e]], 1);
}

__global__ __launch_bounds__(1024) void scan_kernel(const int* __restrict__ degree,
                                                    int* __restrict__ offsets,
                                                    float* __restrict__ logsum, int n) {
    const int T = 1024;
    int tid = threadIdx.x;
    int chunk = (n + T - 1) / T;
    int beg = tid * chunk;
    int end = min(beg + chunk, n);
    if (beg > n) beg = n;
    if (end < beg) end = beg;
    int s = 0;
    float ls = 0.f;
    for (int i = beg; i < end; ++i) {
        int d = degree[i];
        s += d;
        ls += logf((float)d + 2.0f);   // == log1p(d+1)
    }
    __shared__ int part[T];
    __shared__ float fl[T];
    part[tid] = s;
    fl[tid] = ls;
    __syncthreads();
    // Hillis-Steele inclusive scan over int partials
    for (int off = 1; off < T; off <<= 1) {
        int v = (tid >= off) ? part[tid - off] : 0;
        __syncthreads();
        part[tid] += v;
        __syncthreads();
    }
    // tree-reduce float partials for degree_reference
    for (int off = T / 2; off > 0; off >>= 1) {
        if (tid < off) fl[tid] += fl[tid + off];
        __syncthreads();
    }
    if (tid == 0) logsum[0] = fl[0];
    int prefix = (tid == 0) ? 0 : part[tid - 1];
    for (int i = beg; i < end; ++i) {
        offsets[i] = prefix;
        prefix += degree[i];
    }
    if (tid == T - 1) offsets[n] = prefix;
}

__global__ void fill_kernel(const int* __restrict__ ei, const int* __restrict__ offsets,
                            int* __restrict__ cursor, int* __restrict__ csr_src, int E) {
    int e = blockIdx.x * blockDim.x + threadIdx.x;
    if (e < E) {
        int src = ei[e];
        int dst = ei[E + e];
        int pos = offsets[dst] + atomicAdd(&cursor[dst], 1);
        csr_src[pos] = src;
    }
}

// ---------------- Aggregation: one block (128 thr) per node ----------------

__global__ __launch_bounds__(128) void agg_kernel(const float* __restrict__ x,
                                                  const int* __restrict__ csr_src,
                                                  const int* __restrict__ offsets,
                                                  float* __restrict__ Z) {
    int n = blockIdx.x;
    int c = threadIdx.x;   // channel 0..127
    int beg = offsets[n], end = offsets[n + 1];
    float sum = 0.f, mx = -3.402823466e38f;
    __shared__ int s_src[128];
    for (int base = beg; base < end; base += 128) {
        int cnt = min(128, end - base);
        __syncthreads();
        if (c < cnt) s_src[c] = csr_src[base + c];
        __syncthreads();
        for (int i = 0; i < cnt; ++i) {
            float v = x[(long)s_src[i] * IN_CH + c];
            sum += v;
            mx = fmaxf(mx, v);
        }
    }
    int deg = end - beg;
    float* zrow = Z + (long)n * KDIM;
    zrow[c]       = x[(long)n * IN_CH + c];
    zrow[128 + c] = sum;
    zrow[256 + c] = sum / fmaxf((float)deg, 1.f);
    zrow[384 + c] = (deg > 0) ? mx : 0.f;
}

// ---------------- Combined weight build: Wc[512][384] ----------------
// Z col k:  [0,128)=x  [128,256)=sum  [256,384)=mean  [384,512)=max
// G col j = s*128+o, s in {0:id, 1:amp, 2:att}
// stacked block index b = a*3+s  (a in {0:sum,1:mean,2:max})

__global__ void wbuild_kernel(const float* __restrict__ Wmsg, const float* __restrict__ Wroot,
                              float* __restrict__ Wc) {
    int idx = blockIdx.x * blockDim.x + threadIdx.x;
    if (idx >= KDIM * NDIM) return;
    int k = idx / NDIM;
    int j = idx - k * NDIM;
    int s = j >> 7;
    int o = j & 127;
    float v;
    if (k < 128) {
        v = (s == 0) ? Wroot[o * 128 + k] : 0.f;
    } else {
        int a = (k - 128) >> 7;
        int c = (k - 128) & 127;
        v = Wmsg[o * 1152 + (a * 3 + s) * 128 + c];
    }
    Wc[idx] = v;
}

// ---------------- fp32 tiled GEMM: G[M,384] = Z[M,512] @ Wc[512,384] ----------------

#define BM 64
#define BN 64
#define BK 32

__global__ __launch_bounds__(256) void gemm_kernel(const float* __restrict__ A,
                                                   const float* __restrict__ B,
                                                   float* __restrict__ C, int M) {
    __shared__ float As[BK][BM + 4];  // k-major, +4 pad keeps float4 reads 16B-aligned
    __shared__ float Bs[BK][BN + 4];
    int tid = threadIdx.x;
    int row0 = blockIdx.x * BM;
    int col0 = blockIdx.y * BN;
    int ty = tid >> 4;   // 0..15 -> M rows ty*4..ty*4+3
    int tx = tid & 15;   // 0..15 -> N cols tx*4..tx*4+3
    float acc[4][4] = {};
    for (int k0 = 0; k0 < KDIM; k0 += BK) {
        #pragma unroll
        for (int l = 0; l < 2; ++l) {
            int f4 = l * 256 + tid;
            // A tile: 64 rows x 32 k  (512 float4)
            int ar = f4 >> 3;
            int ac = (f4 & 7) * 4;
            float4 v;
            int gr = row0 + ar;
            if (gr < M) v = *(const float4*)&A[(long)gr * KDIM + k0 + ac];
            else        v = make_float4(0.f, 0.f, 0.f, 0.f);
            As[ac + 0][ar] = v.x;
            As[ac + 1][ar] = v.y;
            As[ac + 2][ar] = v.z;
            As[ac + 3][ar] = v.w;
            // B tile: 32 k x 64 cols (512 float4)
            int br = f4 >> 4;
            int bc = (f4 & 15) * 4;
            *(float4*)&Bs[br][bc] = *(const float4*)&B[(long)(k0 + br) * NDIM + col0 + bc];
        }
        __syncthreads();
        #pragma unroll
        for (int k = 0; k < BK; ++k) {
            float4 a = *(const float4*)&As[k][ty * 4];
            float4 b = *(const float4*)&Bs[k][tx * 4];
            acc[0][0] += a.x * b.x; acc[0][1] += a.x * b.y; acc[0][2] += a.x * b.z; acc[0][3] += a.x * b.w;
            acc[1][0] += a.y * b.x; acc[1][1] += a.y * b.y; acc[1][2] += a.y * b.z; acc[1][3] += a.y * b.w;
            acc[2][0] += a.z * b.x; acc[2][1] += a.z * b.y; acc[2][2] += a.z * b.z; acc[2][3] += a.z * b.w;
            acc[3][0] += a.w * b.x; acc[3][1] += a.w * b.y; acc[3][2] += a.w * b.z; acc[3][3] += a.w * b.w;
        }
        __syncthreads();
    }
    #pragma unroll
    for (int i = 0; i < 4; ++i) {
        int gr = row0 + ty * 4 + i;
        if (gr < M) {
            float4 v = make_float4(acc[i][0], acc[i][1], acc[i][2], acc[i][3]);
            *(float4*)&C[(long)gr * NDIM + col0 + tx * 4] = v;
        }
    }
}

// ---------------- Epilogue ----------------

__global__ __launch_bounds__(128) void epilogue_kernel(const float* __restrict__ G,
                                                       const float* __restrict__ bmsg,
                                                       const float* __restrict__ broot,
                                                       const int* __restrict__ degree,
                                                       const float* __restrict__ logsum,
                                                       float* __restrict__ out, int n_nodes) {
    int n = blockIdx.x;
    int o = threadIdx.x;
    float ref = fmaxf(logsum[0] / (float)n_nodes, 1.0f);
    float dt = log1pf((float)degree[n] + 1.0f);
    float amp = dt / ref;
    float att = ref / fmaxf(dt, 1e-6f);
    const float* g = G + (long)n * NDIM;
    out[(long)n * OUT_CH + o] = bmsg[o] + broot[o] + g[o] + amp * g[128 + o] + att * g[256 + o];
}

// ---------------- Launch ----------------

extern "C" void kernel_launch(void* const* d_in, const int* in_sizes, int n_in,
                              void* d_out, int out_size, void* d_ws, size_t ws_size,
                              hipStream_t stream) {
    const float* x     = (const float*)d_in[0];
    const int*   ei    = (const int*)d_in[1];
    const float* Wmsg  = (const float*)d_in[2];
    const float* bmsg  = (const float*)d_in[3];
    const float* Wroot = (const float*)d_in[4];
    const float* broot = (const float*)d_in[5];
    float* out = (float*)d_out;

    int n_nodes = in_sizes[0] / IN_CH;
    int E = in_sizes[1] / 2;

    char* ws = (char*)d_ws;
    size_t off = 0;
    auto alloc = [&](size_t bytes) -> void* {
        void* p = ws + off;
        off = (off + bytes + 255) & ~(size_t)255;
        return p;
    };
    int*   degree  = (int*)alloc((size_t)n_nodes * 4);
    int*   offsets = (int*)alloc((size_t)(n_nodes + 1) * 4);
    int*   cursor  = (int*)alloc((size_t)n_nodes * 4);
    float* logsum  = (float*)alloc(4);
    int*   csr_src = (int*)alloc((size_t)E * 4);
    float* Wc      = (float*)alloc((size_t)KDIM * NDIM * 4);
    float* Z       = (float*)alloc((size_t)n_nodes * KDIM * 4);
    float* G       = (float*)alloc((size_t)n_nodes * NDIM * 4);

    hipMemsetAsync(degree, 0, (size_t)n_nodes * 4, stream);
    hipMemsetAsync(cursor, 0, (size_t)n_nodes * 4, stream);

    degree_kernel<<<(E + 255) / 256, 256, 0, stream>>>(ei, degree, E);
    scan_kernel<<<1, 1024, 0, stream>>>(degree, offsets, logsum, n_nodes);
    fill_kernel<<<(E + 255) / 256, 256, 0, stream>>>(ei, offsets, cursor, csr_src, E);
    agg_kernel<<<n_nodes, 128, 0, stream>>>(x, csr_src, offsets, Z);
    wbuild_kernel<<<(KDIM * NDIM + 255) / 256, 256, 0, stream>>>(Wmsg, Wroot, Wc);
    dim3 ggrid((n_nodes + BM - 1) / BM, NDIM / BN);
    gemm_kernel<<<ggrid, 256, 0, stream>>>(Z, Wc, G, n_nodes);
    epilogue_kernel<<<n_nodes, 128, 0, stream>>>(G, bmsg, broot, degree, logsum, out, n_nodes);
}

// Round 2
// 451.366 us; speedup vs baseline: 1.2615x; 1.2615x over previous
//
#include <hip/hip_runtime.h>
#include <cmath>

#define IN_CH 128
#define OUT_CH 128
#define KDIM 512           // Z row: x(128) | sum(128) | mean(128) | max(128)
#define NGEMM 384          // Wt rows (gemm N): permuted (wavegrp, section, ocol)

typedef __attribute__((ext_vector_type(8))) short bfrag;   // 8 bf16 in 4 VGPRs
typedef __attribute__((ext_vector_type(4))) float f32x4;

// float -> bf16 round-to-nearest-even (bit pattern)
__device__ __forceinline__ unsigned short f2bf(float f) {
    unsigned int u = __float_as_uint(f);
    return (unsigned short)((u + 0x7FFFu + ((u >> 16) & 1u)) >> 16);
}
__device__ __forceinline__ float bf2f(unsigned short h) {
    return __uint_as_float(((unsigned int)h) << 16);
}

// async 16B global->LDS (wave-uniform LDS base + lane*16)
__device__ __forceinline__ void gl2lds16(const void* g, void* l) {
    __builtin_amdgcn_global_load_lds(
        (const __attribute__((address_space(1))) unsigned int*)g,
        (__attribute__((address_space(3))) unsigned int*)l, 16, 0, 0);
}

// ---------------- CSR build ----------------

__global__ void degree_kernel(const int* __restrict__ ei, int* __restrict__ degree, int E) {
    int e = blockIdx.x * blockDim.x + threadIdx.x;
    if (e < E) atomicAdd(&degree[ei[E + e]], 1);
}

__global__ __launch_bounds__(1024) void scan_kernel(const int* __restrict__ degree,
                                                    int* __restrict__ offsets,
                                                    float* __restrict__ logsum, int n) {
    const int T = 1024;
    int tid = threadIdx.x;
    int chunk = (n + T - 1) / T;
    int beg = min(tid * chunk, n);
    int end = min(beg + chunk, n);
    int s = 0;
    float ls = 0.f;
    for (int i = beg; i < end; ++i) {
        int d = degree[i];
        s += d;
        ls += logf((float)d + 2.0f);   // == log1p(d+1)
    }
    __shared__ int part[T];
    __shared__ float fl[T];
    part[tid] = s;
    fl[tid] = ls;
    __syncthreads();
    for (int off = 1; off < T; off <<= 1) {
        int v = (tid >= off) ? part[tid - off] : 0;
        __syncthreads();
        part[tid] += v;
        __syncthreads();
    }
    for (int off = T / 2; off > 0; off >>= 1) {
        if (tid < off) fl[tid] += fl[tid + off];
        __syncthreads();
    }
    if (tid == 0) logsum[0] = fl[0];
    int prefix = (tid == 0) ? 0 : part[tid - 1];
    for (int i = beg; i < end; ++i) {
        offsets[i] = prefix;
        prefix += degree[i];
    }
    if (tid == T - 1) offsets[n] = prefix;
}

__global__ void fill_kernel(const int* __restrict__ ei, const int* __restrict__ offsets,
                            int* __restrict__ cursor, int* __restrict__ csr_src, int E) {
    int e = blockIdx.x * blockDim.x + threadIdx.x;
    if (e < E) {
        int src = ei[e];
        int dst = ei[E + e];
        int pos = offsets[dst] + atomicAdd(&cursor[dst], 1);
        csr_src[pos] = src;
    }
}

// ---------------- Aggregation: one WAVE per node, lane = 2 channels ----------------
// Writes Z as bf16 hi/lo planes [Mpad][512], plus amp/att per node.

__global__ __launch_bounds__(256) void agg_kernel(const float* __restrict__ x,
                                                  const int* __restrict__ csr_src,
                                                  const int* __restrict__ offsets,
                                                  const float* __restrict__ logsum,
                                                  unsigned short* __restrict__ Zhi,
                                                  unsigned short* __restrict__ Zlo,
                                                  float* __restrict__ ampv,
                                                  float* __restrict__ attv,
                                                  int N, int Mpad) {
    int node = (blockIdx.x * 256 + threadIdx.x) >> 6;
    int lane = threadIdx.x & 63;
    if (node >= Mpad) return;
    long zoff = (long)node * KDIM + lane * 2;
    if (node >= N) {   // pad rows: zero so GEMM reads are harmless
        #pragma unroll
        for (int sec = 0; sec < 4; ++sec) {
            *(unsigned int*)&Zhi[zoff + sec * 128] = 0u;
            *(unsigned int*)&Zlo[zoff + sec * 128] = 0u;
        }
        return;
    }
    int beg = offsets[node], end = offsets[node + 1];
    float2 sum = make_float2(0.f, 0.f);
    float2 mx = make_float2(-3.402823466e38f, -3.402823466e38f);
    for (int i = beg; i < end; ++i) {
        int s = csr_src[i];
        float2 v = *(const float2*)&x[(long)s * IN_CH + lane * 2];
        sum.x += v.x; sum.y += v.y;
        mx.x = fmaxf(mx.x, v.x); mx.y = fmaxf(mx.y, v.y);
    }
    int deg = end - beg;
    float inv = 1.0f / fmaxf((float)deg, 1.0f);
    float2 mean = make_float2(sum.x * inv, sum.y * inv);
    if (deg == 0) { mx.x = 0.f; mx.y = 0.f; }
    float2 xv = *(const float2*)&x[(long)node * IN_CH + lane * 2];

    float2 secs[4] = { xv, sum, mean, mx };
    #pragma unroll
    for (int sec = 0; sec < 4; ++sec) {
        float a = secs[sec].x, b = secs[sec].y;
        unsigned short ha = f2bf(a), hb = f2bf(b);
        float la = a - bf2f(ha), lb = b - bf2f(hb);
        unsigned int hi = (unsigned int)ha | ((unsigned int)hb << 16);
        unsigned int lo = (unsigned int)f2bf(la) | ((unsigned int)f2bf(lb) << 16);
        *(unsigned int*)&Zhi[zoff + sec * 128] = hi;
        *(unsigned int*)&Zlo[zoff + sec * 128] = lo;
    }
    if (lane == 0) {
        float ref = fmaxf(logsum[0] / (float)N, 1.0f);
        float dt = log1pf((float)deg + 1.0f);
        ampv[node] = dt / ref;
        attv[node] = ref / fmaxf(dt, 1e-6f);
    }
}

// ---------------- Weight build: Wt[384][512] permuted, transposed, bf16 hi/lo ------
// permuted row j' = (ocol>>5)*96 + s*32 + (ocol&31); value = combined W column for
// gemm: out section s of output col ocol.  k-contiguous rows (1KB) for staging.

__global__ void wbuild_kernel(const float* __restrict__ Wmsg, const float* __restrict__ Wroot,
                              unsigned short* __restrict__ Whi, unsigned short* __restrict__ Wlo) {
    int idx = blockIdx.x * 256 + threadIdx.x;
    if (idx >= NGEMM * KDIM) return;
    int jp = idx >> 9;       // 0..383
    int k = idx & 511;
    int wgrp = jp / 96;
    int rem = jp - wgrp * 96;
    int s = rem >> 5;
    int o = rem & 31;
    int ocol = wgrp * 32 + o;
    float v;
    if (k < 128) {
        v = (s == 0) ? Wroot[ocol * 128 + k] : 0.f;
    } else {
        int a = (k - 128) >> 7;
        int c = (k - 128) & 127;
        v = Wmsg[ocol * 1152 + (a * 3 + s) * 128 + c];
    }
    unsigned short h = f2bf(v);
    Whi[idx] = h;
    Wlo[idx] = f2bf(v - bf2f(h));
}

// ---------------- MFMA GEMM with fused epilogue --------------------------------
// out[M,128] = epilogue( Z[M,512] @ Wt^T[512,384] ), BM=64, BN=384, BK=32.
// Wave w owns gemm cols [96w, 96w+96) = sections (id,amp,att) of out cols [32w,32w+32).
// LDS chunk layout: stripe = 16 rows x 32 k, chunk(row,q) at base + ((q<<4)|row)*16B
// -> both global_load_lds staging and ds_read_b128 frag reads are linear base+lane*16.

__global__ __launch_bounds__(256, 2) void gemm_kernel(const unsigned short* __restrict__ Zhi,
                                                      const unsigned short* __restrict__ Zlo,
                                                      const unsigned short* __restrict__ Whi,
                                                      const unsigned short* __restrict__ Wlo,
                                                      const float* __restrict__ ampv,
                                                      const float* __restrict__ attv,
                                                      const float* __restrict__ bmsg,
                                                      const float* __restrict__ broot,
                                                      float* __restrict__ out, int M) {
    // ushort units: Ahi [0,2048) Alo [2048,4096) Bhi [4096,16384) Blo [16384,28672)
    __shared__ unsigned short lds[28672];   // 56 KB
    const int tid = threadIdx.x;
    const int w = tid >> 6;
    const int lane = tid & 63;
    const int row0 = blockIdx.x * 64;
    const int r16 = lane & 15, q = lane >> 4;

    f32x4 acc[4][6] = {};

    // per-lane global element offsets (ushort units), advance by 32 per K-step
    long ga = (long)(row0 + w * 16 + r16) * KDIM + q * 8;        // into Zhi/Zlo
    for (int k0 = 0; k0 < KDIM; k0 += 32) {
        if (k0) __syncthreads();
        // stage A (this wave's 16-row stripe), hi+lo
        gl2lds16(Zhi + ga + k0, &lds[w * 512]);
        gl2lds16(Zlo + ga + k0, &lds[2048 + w * 512]);
        // stage B: wave w stages stripes 6w..6w+5, hi+lo
        #pragma unroll
        for (int t = 0; t < 6; ++t) {
            int st = 6 * w + t;
            long gb = (long)(st * 16 + r16) * KDIM + k0 + q * 8;
            gl2lds16(Whi + gb, &lds[4096 + st * 512]);
            gl2lds16(Wlo + gb, &lds[16384 + st * 512]);
        }
        __syncthreads();

        bfrag ah[4], al[4];
        #pragma unroll
        for (int mt = 0; mt < 4; ++mt) {
            ah[mt] = *(const bfrag*)&lds[mt * 512 + lane * 8];
            al[mt] = *(const bfrag*)&lds[2048 + mt * 512 + lane * 8];
        }
        #pragma unroll
        for (int t = 0; t < 6; ++t) {
            int st = 6 * w + t;
            bfrag bh = *(const bfrag*)&lds[4096 + st * 512 + lane * 8];
            bfrag bl = *(const bfrag*)&lds[16384 + st * 512 + lane * 8];
            #pragma unroll
            for (int mt = 0; mt < 4; ++mt) {
                acc[mt][t] = __builtin_amdgcn_mfma_f32_16x16x32_bf16(ah[mt], bh, acc[mt][t], 0, 0, 0);
                acc[mt][t] = __builtin_amdgcn_mfma_f32_16x16x32_bf16(ah[mt], bl, acc[mt][t], 0, 0, 0);
                acc[mt][t] = __builtin_amdgcn_mfma_f32_16x16x32_bf16(al[mt], bh, acc[mt][t], 0, 0, 0);
            }
        }
    }

    // fused epilogue: C/D layout col=lane&15, row=quad*4+reg  (verified m89/m91)
    #pragma unroll
    for (int g = 0; g < 2; ++g) {
        int col = w * 32 + g * 16 + r16;
        float bias = bmsg[col] + broot[col];
        #pragma unroll
        for (int mt = 0; mt < 4; ++mt) {
            #pragma unroll
            for (int r = 0; r < 4; ++r) {
                int row = row0 + mt * 16 + q * 4 + r;
                if (row < M) {
                    float v = acc[mt][g][r]
                            + ampv[row] * acc[mt][2 + g][r]
                            + attv[row] * acc[mt][4 + g][r] + bias;
                    out[(long)row * OUT_CH + col] = v;
                }
            }
        }
    }
}

// ---------------- Launch ----------------

extern "C" void kernel_launch(void* const* d_in, const int* in_sizes, int n_in,
                              void* d_out, int out_size, void* d_ws, size_t ws_size,
                              hipStream_t stream) {
    const float* x     = (const float*)d_in[0];
    const int*   ei    = (const int*)d_in[1];
    const float* Wmsg  = (const float*)d_in[2];
    const float* bmsg  = (const float*)d_in[3];
    const float* Wroot = (const float*)d_in[4];
    const float* broot = (const float*)d_in[5];
    float* out = (float*)d_out;

    int N = in_sizes[0] / IN_CH;           // 50000
    int E = in_sizes[1] / 2;               // 600000
    int nblk = (N + 63) / 64;              // 782
    int Mpad = nblk * 64;                  // 50048

    char* ws = (char*)d_ws;
    size_t off = 0;
    auto alloc = [&](size_t bytes) -> void* {
        void* p = ws + off;
        off = (off + bytes + 255) & ~(size_t)255;
        return p;
    };
    int* degree  = (int*)alloc((size_t)N * 4);
    int* offsets = (int*)alloc((size_t)(N + 1) * 4);
    int* cursor  = (int*)alloc((size_t)N * 4);
    float* logsum = (float*)alloc(4);
    int* csr_src = (int*)alloc((size_t)E * 4);
    unsigned short* Whi = (unsigned short*)alloc((size_t)NGEMM * KDIM * 2);
    unsigned short* Wlo = (unsigned short*)alloc((size_t)NGEMM * KDIM * 2);
    unsigned short* Zhi = (unsigned short*)alloc((size_t)Mpad * KDIM * 2);
    unsigned short* Zlo = (unsigned short*)alloc((size_t)Mpad * KDIM * 2);
    float* ampv = (float*)alloc((size_t)N * 4);
    float* attv = (float*)alloc((size_t)N * 4);

    hipMemsetAsync(degree, 0, (size_t)N * 4, stream);
    hipMemsetAsync(cursor, 0, (size_t)N * 4, stream);

    degree_kernel<<<(E + 255) / 256, 256, 0, stream>>>(ei, degree, E);
    scan_kernel<<<1, 1024, 0, stream>>>(degree, offsets, logsum, N);
    fill_kernel<<<(E + 255) / 256, 256, 0, stream>>>(ei, offsets, cursor, csr_src, E);
    agg_kernel<<<(Mpad * 64 + 255) / 256, 256, 0, stream>>>(x, csr_src, offsets, logsum,
                                                            Zhi, Zlo, ampv, attv, N, Mpad);
    wbuild_kernel<<<(NGEMM * KDIM + 255) / 256, 256, 0, stream>>>(Wmsg, Wroot, Whi, Wlo);
    gemm_kernel<<<nblk, 256, 0, stream>>>(Zhi, Zlo, Whi, Wlo, ampv, attv, bmsg, broot, out, N);
}

// Round 4
// 439.588 us; speedup vs baseline: 1.2953x; 1.0268x over previous
//
#include <hip/hip_runtime.h>
#include <cmath>

#define IN_CH 128
#define OUT_CH 128
#define KDIM 512           // Z row: x(128) | sum(128) | mean(128) | max(128)
#define NGEMM 384          // gemm N: permuted (wavegrp, section, ocol)

typedef __attribute__((ext_vector_type(8))) short bfrag;   // 8 bf16 in 4 VGPRs
typedef __attribute__((ext_vector_type(4))) float f32x4;

// float -> bf16 round-to-nearest-even (bit pattern)
__device__ __forceinline__ unsigned short f2bf(float f) {
    unsigned int u = __float_as_uint(f);
    return (unsigned short)((u + 0x7FFFu + ((u >> 16) & 1u)) >> 16);
}
__device__ __forceinline__ float bf2f(unsigned short h) {
    return __uint_as_float(((unsigned int)h) << 16);
}

// ---------------- CSR build ----------------

__global__ void degree_kernel(const int* __restrict__ ei, int* __restrict__ degree, int E) {
    int e = blockIdx.x * blockDim.x + threadIdx.x;
    if (e < E) atomicAdd(&degree[ei[E + e]], 1);
}

__global__ __launch_bounds__(1024) void scan_kernel(const int* __restrict__ degree,
                                                    int* __restrict__ offsets,
                                                    float* __restrict__ logsum, int n) {
    const int T = 1024;
    int tid = threadIdx.x;
    int chunk = (n + T - 1) / T;
    int beg = min(tid * chunk, n);
    int end = min(beg + chunk, n);
    int s = 0;
    float ls = 0.f;
    for (int i = beg; i < end; ++i) {
        int d = degree[i];
        s += d;
        ls += logf((float)d + 2.0f);   // == log1p(d+1)
    }
    __shared__ int part[T];
    __shared__ float fl[T];
    part[tid] = s;
    fl[tid] = ls;
    __syncthreads();
    for (int off = 1; off < T; off <<= 1) {
        int v = (tid >= off) ? part[tid - off] : 0;
        __syncthreads();
        part[tid] += v;
        __syncthreads();
    }
    for (int off = T / 2; off > 0; off >>= 1) {
        if (tid < off) fl[tid] += fl[tid + off];
        __syncthreads();
    }
    if (tid == 0) logsum[0] = fl[0];
    int prefix = (tid == 0) ? 0 : part[tid - 1];
    for (int i = beg; i < end; ++i) {
        offsets[i] = prefix;
        prefix += degree[i];
    }
    if (tid == T - 1) offsets[n] = prefix;
}

__global__ void fill_kernel(const int* __restrict__ ei, const int* __restrict__ offsets,
                            int* __restrict__ cursor, int* __restrict__ csr_src, int E) {
    int e = blockIdx.x * blockDim.x + threadIdx.x;
    if (e < E) {
        int src = ei[e];
        int dst = ei[E + e];
        int pos = offsets[dst] + atomicAdd(&cursor[dst], 1);
        csr_src[pos] = src;
    }
}

// ---------------- Aggregation: one WAVE per node, lane = 2 channels ----------------
// Unroll-4 with independent accumulators: 4 gather chains in flight per wave.

__global__ __launch_bounds__(256) void agg_kernel(const float* __restrict__ x,
                                                  const int* __restrict__ csr_src,
                                                  const int* __restrict__ offsets,
                                                  const float* __restrict__ logsum,
                                                  unsigned short* __restrict__ Zhi,
                                                  unsigned short* __restrict__ Zlo,
                                                  float* __restrict__ ampv,
                                                  float* __restrict__ attv,
                                                  int N, int Mpad) {
    int node = (blockIdx.x * 256 + threadIdx.x) >> 6;
    int lane = threadIdx.x & 63;
    if (node >= Mpad) return;
    long zoff = (long)node * KDIM + lane * 2;
    if (node >= N) {   // pad rows: zero so GEMM reads are harmless
        #pragma unroll
        for (int sec = 0; sec < 4; ++sec) {
            *(unsigned int*)&Zhi[zoff + sec * 128] = 0u;
            *(unsigned int*)&Zlo[zoff + sec * 128] = 0u;
        }
        return;
    }
    int beg = offsets[node], end = offsets[node + 1];
    const float NEG = -3.402823466e38f;
    float2 s0 = {0.f, 0.f}, s1 = {0.f, 0.f}, s2 = {0.f, 0.f}, s3 = {0.f, 0.f};
    float2 m0 = {NEG, NEG}, m1 = {NEG, NEG}, m2 = {NEG, NEG}, m3 = {NEG, NEG};
    int i = beg;
    for (; i + 4 <= end; i += 4) {
        int n0 = csr_src[i], n1 = csr_src[i + 1], n2 = csr_src[i + 2], n3 = csr_src[i + 3];
        float2 v0 = *(const float2*)&x[(long)n0 * IN_CH + lane * 2];
        float2 v1 = *(const float2*)&x[(long)n1 * IN_CH + lane * 2];
        float2 v2 = *(const float2*)&x[(long)n2 * IN_CH + lane * 2];
        float2 v3 = *(const float2*)&x[(long)n3 * IN_CH + lane * 2];
        s0.x += v0.x; s0.y += v0.y; m0.x = fmaxf(m0.x, v0.x); m0.y = fmaxf(m0.y, v0.y);
        s1.x += v1.x; s1.y += v1.y; m1.x = fmaxf(m1.x, v1.x); m1.y = fmaxf(m1.y, v1.y);
        s2.x += v2.x; s2.y += v2.y; m2.x = fmaxf(m2.x, v2.x); m2.y = fmaxf(m2.y, v2.y);
        s3.x += v3.x; s3.y += v3.y; m3.x = fmaxf(m3.x, v3.x); m3.y = fmaxf(m3.y, v3.y);
    }
    for (; i < end; ++i) {
        int n0 = csr_src[i];
        float2 v0 = *(const float2*)&x[(long)n0 * IN_CH + lane * 2];
        s0.x += v0.x; s0.y += v0.y; m0.x = fmaxf(m0.x, v0.x); m0.y = fmaxf(m0.y, v0.y);
    }
    float2 sum = make_float2((s0.x + s1.x) + (s2.x + s3.x), (s0.y + s1.y) + (s2.y + s3.y));
    float2 mx = make_float2(fmaxf(fmaxf(m0.x, m1.x), fmaxf(m2.x, m3.x)),
                            fmaxf(fmaxf(m0.y, m1.y), fmaxf(m2.y, m3.y)));
    int deg = end - beg;
    float inv = 1.0f / fmaxf((float)deg, 1.0f);
    float2 mean = make_float2(sum.x * inv, sum.y * inv);
    if (deg == 0) { mx.x = 0.f; mx.y = 0.f; }
    float2 xv = *(const float2*)&x[(long)node * IN_CH + lane * 2];

    float2 secs[4] = { xv, sum, mean, mx };
    #pragma unroll
    for (int sec = 0; sec < 4; ++sec) {
        float a = secs[sec].x, b = secs[sec].y;
        unsigned short ha = f2bf(a), hb = f2bf(b);
        float la = a - bf2f(ha), lb = b - bf2f(hb);
        unsigned int hi = (unsigned int)ha | ((unsigned int)hb << 16);
        unsigned int lo = (unsigned int)f2bf(la) | ((unsigned int)f2bf(lb) << 16);
        *(unsigned int*)&Zhi[zoff + sec * 128] = hi;
        *(unsigned int*)&Zlo[zoff + sec * 128] = lo;
    }
    if (lane == 0) {
        float ref = fmaxf(logsum[0] / (float)N, 1.0f);
        float dt = log1pf((float)deg + 1.0f);
        ampv[node] = dt / ref;
        attv[node] = ref / fmaxf(dt, 1e-6f);
    }
}

// ---------------- Weight build: frag-major B, bf16 hi/lo --------------------------
// Bf flat idx = ((st*16 + ks)*64 + lane)*8 + e  ->  W^T[jp][k] where
// r16=lane&15, q=lane>>4, jp = st*16 + r16, k = ks*32 + q*8 + e.
// jp -> (wgrp = jp/96, s = (jp%96)>>5, o = jp&31), ocol = wgrp*32 + o.
// gemm B loads become linear 1KB/wave (perfect coalescing), no LDS needed.

__global__ void wbuild_kernel(const float* __restrict__ Wmsg, const float* __restrict__ Wroot,
                              unsigned short* __restrict__ Whi, unsigned short* __restrict__ Wlo) {
    int idx = blockIdx.x * 256 + threadIdx.x;
    if (idx >= NGEMM * KDIM) return;
    int e = idx & 7;
    int lane = (idx >> 3) & 63;
    int t2 = idx >> 9;
    int ks = t2 & 15;
    int st = t2 >> 4;                 // 0..23
    int r16 = lane & 15, q = lane >> 4;
    int jp = st * 16 + r16;
    int k = ks * 32 + q * 8 + e;
    int wgrp = jp / 96;
    int rem = jp - wgrp * 96;
    int s = rem >> 5;
    int ocol = wgrp * 32 + (rem & 31);
    float v;
    if (k < 128) {
        v = (s == 0) ? Wroot[ocol * 128 + k] : 0.f;
    } else {
        int a = (k - 128) >> 7;
        int c = (k - 128) & 127;
        v = Wmsg[ocol * 1152 + (a * 3 + s) * 128 + c];
    }
    unsigned short h = f2bf(v);
    Whi[idx] = h;
    Wlo[idx] = f2bf(v - bf2f(h));
}

// ---------------- MFMA GEMM, zero LDS, zero barriers ------------------------------
// out[M,128] = epilogue( Z[M,512] @ Wt^T ).  Block = 4 waves, 64 rows.
// Wave w owns gemm cols [96w,96w+96) = stripes 6w..6w+5.
// A frags straight from row-major Zhi/Zlo (16x64B segments per load);
// B frags from frag-major Whi/Wlo (linear 1KB per wave-load, L2-resident).
// No __syncthreads anywhere -> compiler pipelines loads across K with vmcnt(N).

__global__ __launch_bounds__(256, 2) void gemm_kernel(const unsigned short* __restrict__ Zhi,
                                                      const unsigned short* __restrict__ Zlo,
                                                      const unsigned short* __restrict__ Whi,
                                                      const unsigned short* __restrict__ Wlo,
                                                      const float* __restrict__ ampv,
                                                      const float* __restrict__ attv,
                                                      const float* __restrict__ bmsg,
                                                      const float* __restrict__ broot,
                                                      float* __restrict__ out, int M) {
    const int tid = threadIdx.x;
    const int w = tid >> 6;
    const int lane = tid & 63;
    const int row0 = blockIdx.x * 64;
    const int r16 = lane & 15, q = lane >> 4;

    f32x4 acc[4][6] = {};

    const unsigned short* pah[4];
    const unsigned short* pal[4];
    #pragma unroll
    for (int mt = 0; mt < 4; ++mt) {
        long o = (long)(row0 + mt * 16 + r16) * KDIM + q * 8;
        pah[mt] = Zhi + o;
        pal[mt] = Zlo + o;
    }
    // B: idx(st,ks,lane,e) = st*8192 + ks*512 + lane*8 + e
    const unsigned short* pbh = Whi + (6 * w) * 8192 + lane * 8;
    const unsigned short* pbl = Wlo + (6 * w) * 8192 + lane * 8;

    for (int ks = 0; ks < 16; ++ks) {
        bfrag ah[4], al[4], bh[6], bl[6];
        #pragma unroll
        for (int mt = 0; mt < 4; ++mt) {
            ah[mt] = *(const bfrag*)pah[mt];
            al[mt] = *(const bfrag*)pal[mt];
            pah[mt] += 32;
            pal[mt] += 32;
        }
        #pragma unroll
        for (int t = 0; t < 6; ++t) {
            bh[t] = *(const bfrag*)(pbh + t * 8192);
            bl[t] = *(const bfrag*)(pbl + t * 8192);
        }
        pbh += 512;
        pbl += 512;
        #pragma unroll
        for (int t = 0; t < 6; ++t) {
            #pragma unroll
            for (int mt = 0; mt < 4; ++mt) {
                acc[mt][t] = __builtin_amdgcn_mfma_f32_16x16x32_bf16(ah[mt], bh[t], acc[mt][t], 0, 0, 0);
                acc[mt][t] = __builtin_amdgcn_mfma_f32_16x16x32_bf16(ah[mt], bl[t], acc[mt][t], 0, 0, 0);
                acc[mt][t] = __builtin_amdgcn_mfma_f32_16x16x32_bf16(al[mt], bh[t], acc[mt][t], 0, 0, 0);
            }
        }
    }

    // fused epilogue: C/D layout col=lane&15, row=quad*4+reg  (verified m89/m91)
    #pragma unroll
    for (int g = 0; g < 2; ++g) {
        int col = w * 32 + g * 16 + r16;
        float bias = bmsg[col] + broot[col];
        #pragma unroll
        for (int mt = 0; mt < 4; ++mt) {
            #pragma unroll
            for (int r = 0; r < 4; ++r) {
                int row = row0 + mt * 16 + q * 4 + r;
                if (row < M) {
                    float v = acc[mt][g][r]
                            + ampv[row] * acc[mt][2 + g][r]
                            + attv[row] * acc[mt][4 + g][r] + bias;
                    out[(long)row * OUT_CH + col] = v;
                }
            }
        }
    }
}

// ---------------- Launch ----------------

extern "C" void kernel_launch(void* const* d_in, const int* in_sizes, int n_in,
                              void* d_out, int out_size, void* d_ws, size_t ws_size,
                              hipStream_t stream) {
    const float* x     = (const float*)d_in[0];
    const int*   ei    = (const int*)d_in[1];
    const float* Wmsg  = (const float*)d_in[2];
    const float* bmsg  = (const float*)d_in[3];
    const float* Wroot = (const float*)d_in[4];
    const float* broot = (const float*)d_in[5];
    float* out = (float*)d_out;

    int N = in_sizes[0] / IN_CH;           // 50000
    int E = in_sizes[1] / 2;               // 600000
    int nblk = (N + 63) / 64;              // 782
    int Mpad = nblk * 64;                  // 50048

    char* ws = (char*)d_ws;
    size_t off = 0;
    auto alloc = [&](size_t bytes) -> void* {
        void* p = ws + off;
        off = (off + bytes + 255) & ~(size_t)255;
        return p;
    };
    int* degree  = (int*)alloc((size_t)N * 4);
    int* offsets = (int*)alloc((size_t)(N + 1) * 4);
    int* cursor  = (int*)alloc((size_t)N * 4);
    float* logsum = (float*)alloc(4);
    int* csr_src = (int*)alloc((size_t)E * 4);
    unsigned short* Whi = (unsigned short*)alloc((size_t)NGEMM * KDIM * 2);
    unsigned short* Wlo = (unsigned short*)alloc((size_t)NGEMM * KDIM * 2);
    unsigned short* Zhi = (unsigned short*)alloc((size_t)Mpad * KDIM * 2);
    unsigned short* Zlo = (unsigned short*)alloc((size_t)Mpad * KDIM * 2);
    float* ampv = (float*)alloc((size_t)N * 4);
    float* attv = (float*)alloc((size_t)N * 4);

    hipMemsetAsync(degree, 0, (size_t)N * 4, stream);
    hipMemsetAsync(cursor, 0, (size_t)N * 4, stream);

    degree_kernel<<<(E + 255) / 256, 256, 0, stream>>>(ei, degree, E);
    scan_kernel<<<1, 1024, 0, stream>>>(degree, offsets, logsum, N);
    fill_kernel<<<(E + 255) / 256, 256, 0, stream>>>(ei, offsets, cursor, csr_src, E);
    agg_kernel<<<(Mpad * 64 + 255) / 256, 256, 0, stream>>>(x, csr_src, offsets, logsum,
                                                            Zhi, Zlo, ampv, attv, N, Mpad);
    wbuild_kernel<<<(NGEMM * KDIM + 255) / 256, 256, 0, stream>>>(Wmsg, Wroot, Whi, Wlo);
    gemm_kernel<<<nblk, 256, 0, stream>>>(Zhi, Zlo, Whi, Wlo, ampv, attv, bmsg, broot, out, N);
}